// Round 3
// baseline (481.800 us; speedup 1.0000x reference)
//
#include <hip/hip_runtime.h>
#include <hip/hip_bf16.h>

typedef __attribute__((ext_vector_type(8))) short bf16x8;
typedef __attribute__((ext_vector_type(4))) float f32x4;

#define NQ 2500
#define NKK 6336
#define NHEADS 4
#define DHEAD 32
#define SCALE 0.17677669529663687f
#define BIGNEG (-1.0e30f)

// workspace byte offsets (all 16B aligned)
#define WS_QP 0
#define WS_KP 640000
#define WS_VT 2262016
#define WS_OP 3884032
#define WS_MP 7724032
#define WS_LP 7844032
#define WS_FLAG 7964032
#define WS_REQ 7964048

#define KSPLIT 3
#define SPLIT_LEN 2112
#define TILES_PER_SPLIT 33
#define TQ 16
#define TK 64
#define QBLOCKS 157

#define QSTR 136
#define KSTR 136
#define VSTR 72
#define PSTR 72

// ---- dtype-adaptive scalar load ----
template<typename TI> struct LD;
template<> struct LD<__hip_bfloat16> {
  static __device__ __forceinline__ float ld(const void* p, size_t i) {
    return __bfloat162float(((const __hip_bfloat16*)p)[i]);
  }
};
template<> struct LD<float> {
  static __device__ __forceinline__ float ld(const void* p, size_t i) {
    return ((const float*)p)[i];
  }
};

// Probe: qn_g is all ones. fp32 1.0f -> 0x3F800000 ; two bf16 1.0 -> 0x3F803F80
__global__ void probe_kernel(const unsigned* __restrict__ qn_g_u32, int* __restrict__ flag) {
  if (threadIdx.x == 0 && blockIdx.x == 0)
    *flag = (qn_g_u32[0] == 0x3F800000u) ? 1 : 0;
}

__device__ __forceinline__ void ln_stats128(float x, float* sred, float& mean, float& rstd) {
  float s = x, ss = x * x;
  #pragma unroll
  for (int off = 32; off > 0; off >>= 1) {
    s += __shfl_down(s, off);
    ss += __shfl_down(ss, off);
  }
  int wid = threadIdx.x >> 6;
  if ((threadIdx.x & 63) == 0) { sred[wid * 2] = s; sred[wid * 2 + 1] = ss; }
  __syncthreads();
  float S = sred[0] + sred[2];
  float SS = sred[1] + sred[3];
  mean = S * (1.0f / 128.0f);
  float var = SS * (1.0f / 128.0f) - mean * mean;
  rstd = rsqrtf(fmaxf(var, 0.0f) + 1e-5f);
  __syncthreads();
}

// ---------------- lnproj ----------------
template<typename TI>
__device__ __forceinline__ void lnproj_body(
    const void* qin, const void* kin, const void* vin,
    const void* qn_g, const void* qn_b, const void* kn_g, const void* kn_b,
    const void* vn_g, const void* vn_b,
    const void* wq, const void* bq, const void* wk, const void* bk,
    const void* wv, const void* bv,
    __hip_bfloat16* Qp, __hip_bfloat16* Kp, __hip_bfloat16* Vt,
    float* sx, float* sred)
{
  const int t = threadIdx.x;
  const int bb = blockIdx.x;

  float x;
  const void *g, *be, *w, *bo;
  int mode, row;
  if (bb < NQ) {
    mode = 0; row = bb;
    x = LD<TI>::ld(qin, (size_t)t * NQ + row);
    g = qn_g; be = qn_b; w = wq; bo = bq;
  } else if (bb < NQ + NKK) {
    mode = 1; row = bb - NQ;
    int n = row / 1056, r = row - n * 1056;
    x = LD<TI>::ld(kin, (size_t)n * 135168 + (size_t)t * 1056 + r);
    g = kn_g; be = kn_b; w = wk; bo = bk;
  } else {
    mode = 2; row = bb - (NQ + NKK);
    int n = row / 1056, r = row - n * 1056;
    x = LD<TI>::ld(vin, (size_t)n * 135168 + (size_t)t * 1056 + r);
    g = vn_g; be = vn_b; w = wv; bo = bv;
  }
  float mean, rstd;
  ln_stats128(x, sred, mean, rstd);
  float xn = (x - mean) * rstd * LD<TI>::ld(g, t) + LD<TI>::ld(be, t);
  sx[t] = xn;
  __syncthreads();

  float acc = LD<TI>::ld(bo, t);
  #pragma unroll 8
  for (int d = 0; d < 128; ++d)
    acc += sx[d] * LD<TI>::ld(w, (size_t)t * 128 + d);

  __hip_bfloat16 r16 = __float2bfloat16(acc);
  if (mode == 0)      Qp[(size_t)row * 128 + t] = r16;
  else if (mode == 1) Kp[(size_t)row * 128 + t] = r16;
  else                Vt[(size_t)t * NKK + row] = r16;
}

__global__ __launch_bounds__(128) void lnproj_kernel(
    const void* qin, const void* kin, const void* vin,
    const void* qn_g, const void* qn_b, const void* kn_g, const void* kn_b,
    const void* vn_g, const void* vn_b,
    const void* wq, const void* bq, const void* wk, const void* bk,
    const void* wv, const void* bv,
    __hip_bfloat16* Qp, __hip_bfloat16* Kp, __hip_bfloat16* Vt,
    const int* __restrict__ flag)
{
  __shared__ float sx[128];
  __shared__ float sred[4];
  if (*flag)
    lnproj_body<float>(qin, kin, vin, qn_g, qn_b, kn_g, kn_b, vn_g, vn_b,
                       wq, bq, wk, bk, wv, bv, Qp, Kp, Vt, sx, sred);
  else
    lnproj_body<__hip_bfloat16>(qin, kin, vin, qn_g, qn_b, kn_g, kn_b, vn_g, vn_b,
                                wq, bq, wk, bk, wv, bv, Qp, Kp, Vt, sx, sred);
}

// ---------------- attention ----------------
template<typename TI>
__device__ __forceinline__ void attn_body(
    const __hip_bfloat16* __restrict__ Qp,
    const __hip_bfloat16* __restrict__ Kp,
    const __hip_bfloat16* __restrict__ Vt,
    const void* __restrict__ Wl,
    const int* __restrict__ vis,
    float* __restrict__ Opart, float* __restrict__ Mpart, float* __restrict__ Lpart,
    __hip_bfloat16* lq, __hip_bfloat16* lk, __hip_bfloat16* lv,
    float2* lab, __hip_bfloat16* lp)
{
  const int t = threadIdx.x;
  const int lane = t & 63;
  const int h = t >> 6;
  const int n16 = lane & 15;
  const int quad = lane >> 4;
  const int q0 = blockIdx.x * TQ;
  const int split = blockIdx.y;
  const int kbase = split * SPLIT_LEN;

  // stage Q tile [16][128]
  {
    int e = t * 8;
    int r = e >> 7, c = e & 127;
    int gq = q0 + r;
    uint4 val = make_uint4(0u, 0u, 0u, 0u);
    if (gq < NQ) val = *(const uint4*)(Qp + (size_t)gq * 128 + c);
    *(uint4*)&lq[r * QSTR + c] = val;
  }
  __syncthreads();

  bf16x8 aq = *(const bf16x8*)&lq[n16 * QSTR + h * DHEAD + quad * 8];

  f32x4 o0 = {0.f, 0.f, 0.f, 0.f};
  f32x4 o1 = {0.f, 0.f, 0.f, 0.f};
  float m_run[4], l_run[4];
  #pragma unroll
  for (int r = 0; r < 4; ++r) { m_run[r] = BIGNEG; l_run[r] = 0.f; }

  for (int kt = 0; kt < TILES_PER_SPLIT; ++kt) {
    const int k0 = kbase + kt * TK;
    { // K tile [64 keys][128 d]
      int r = t >> 2, c0 = (t & 3) * 32;
      const uint4* src = (const uint4*)(Kp + (size_t)(k0 + r) * 128 + c0);
      uint4* dst = (uint4*)&lk[r * KSTR + c0];
      #pragma unroll
      for (int i = 0; i < 4; ++i) dst[i] = src[i];
    }
    { // V tile (transposed): [128 d][64 keys]
      int r = t >> 1, c0 = (t & 1) * 32;
      const uint4* src = (const uint4*)(Vt + (size_t)r * NKK + k0 + c0);
      uint4* dst = (uint4*)&lv[r * VSTR + c0];
      #pragma unroll
      for (int i = 0; i < 4; ++i) dst[i] = src[i];
    }
    { // (a,b) tile: logit = s*a + b  reproduces (vis? s*scale : BIGNEG)*W
      int e = t * 4;
      int qq = e >> 6, kk = e & 63;
      int gq = q0 + qq; if (gq > NQ - 1) gq = NQ - 1;
      size_t base = (size_t)gq * NKK + k0 + kk;
      float wf[4];
      if constexpr (sizeof(TI) == 4) {
        float4 w4 = *(const float4*)((const float*)Wl + base);
        wf[0] = w4.x; wf[1] = w4.y; wf[2] = w4.z; wf[3] = w4.w;
      } else {
        ushort4 w4 = *(const ushort4*)((const __hip_bfloat16*)Wl + base);
        wf[0] = __uint_as_float((unsigned)(unsigned short)w4.x << 16);
        wf[1] = __uint_as_float((unsigned)(unsigned short)w4.y << 16);
        wf[2] = __uint_as_float((unsigned)(unsigned short)w4.z << 16);
        wf[3] = __uint_as_float((unsigned)(unsigned short)w4.w << 16);
      }
      int4 v4 = *(const int4*)(vis + base);
      int vv[4] = {v4.x, v4.y, v4.z, v4.w};
      #pragma unroll
      for (int j = 0; j < 4; ++j) {
        float a = vv[j] ? wf[j] * SCALE : 0.f;
        float b = vv[j] ? 0.f : BIGNEG * wf[j];
        lab[e + j] = make_float2(a, b);
      }
    }
    __syncthreads();

    // S = Q K^T (per head): 4 MFMAs covering 16q x 64k
    f32x4 s[4];
    #pragma unroll
    for (int ks = 0; ks < 4; ++ks) {
      bf16x8 bk = *(const bf16x8*)&lk[(ks * 16 + n16) * KSTR + h * DHEAD + quad * 8];
      f32x4 z = {0.f, 0.f, 0.f, 0.f};
      s[ks] = __builtin_amdgcn_mfma_f32_16x16x32_bf16(aq, bk, z, 0, 0, 0);
    }

    // logits with mask/W folded in; C-layout: row=quad*4+reg, col=ks*16+n16
    float lvv[4][4];
    #pragma unroll
    for (int ks = 0; ks < 4; ++ks) {
      #pragma unroll
      for (int r = 0; r < 4; ++r) {
        float2 ab = lab[(quad * 4 + r) * TK + ks * 16 + n16];
        lvv[ks][r] = s[ks][r] * ab.x + ab.y;
      }
    }
    // online softmax per q-row (rows live across the 16 lanes of a quad)
    float alpha[4];
    #pragma unroll
    for (int r = 0; r < 4; ++r) {
      float tm = fmaxf(fmaxf(lvv[0][r], lvv[1][r]), fmaxf(lvv[2][r], lvv[3][r]));
      tm = fmaxf(tm, __shfl_xor(tm, 1));
      tm = fmaxf(tm, __shfl_xor(tm, 2));
      tm = fmaxf(tm, __shfl_xor(tm, 4));
      tm = fmaxf(tm, __shfl_xor(tm, 8));
      float m_new = fmaxf(m_run[r], tm);
      alpha[r] = __expf(m_run[r] - m_new);
      m_run[r] = m_new;
      float ssum = 0.f;
      #pragma unroll
      for (int ks = 0; ks < 4; ++ks) {
        float p = __expf(fmaxf(lvv[ks][r] - m_new, BIGNEG));
        lvv[ks][r] = p;
        ssum += p;
      }
      ssum += __shfl_xor(ssum, 1);
      ssum += __shfl_xor(ssum, 2);
      ssum += __shfl_xor(ssum, 4);
      ssum += __shfl_xor(ssum, 8);
      l_run[r] = l_run[r] * alpha[r] + ssum;
    }
    // P: C-layout -> LDS -> A-layout (per-head section, intra-wave only)
    #pragma unroll
    for (int ks = 0; ks < 4; ++ks) {
      #pragma unroll
      for (int r = 0; r < 4; ++r)
        lp[h * (TQ * PSTR) + (quad * 4 + r) * PSTR + ks * 16 + n16] = __float2bfloat16(lvv[ks][r]);
    }
    // rescale O then accumulate P@V
    #pragma unroll
    for (int r = 0; r < 4; ++r) { o0[r] *= alpha[r]; o1[r] *= alpha[r]; }

    #pragma unroll
    for (int kk = 0; kk < 2; ++kk) {
      bf16x8 ap  = *(const bf16x8*)&lp[h * (TQ * PSTR) + n16 * PSTR + kk * 32 + quad * 8];
      bf16x8 bv0 = *(const bf16x8*)&lv[(h * DHEAD + n16) * VSTR + kk * 32 + quad * 8];
      bf16x8 bv1 = *(const bf16x8*)&lv[(h * DHEAD + 16 + n16) * VSTR + kk * 32 + quad * 8];
      o0 = __builtin_amdgcn_mfma_f32_16x16x32_bf16(ap, bv0, o0, 0, 0, 0);
      o1 = __builtin_amdgcn_mfma_f32_16x16x32_bf16(ap, bv1, o1, 0, 0, 0);
    }
    __syncthreads();
  }

  // epilogue: unnormalized O + (m,l) per split
  #pragma unroll
  for (int r = 0; r < 4; ++r) {
    int gq = q0 + quad * 4 + r;
    if (gq < NQ) {
      size_t ob = (size_t)split * (NQ * 128) + (size_t)gq * 128 + h * DHEAD;
      Opart[ob + n16] = o0[r];
      Opart[ob + 16 + n16] = o1[r];
      if (n16 == 0) {
        Mpart[((size_t)split * NHEADS + h) * NQ + gq] = m_run[r];
        Lpart[((size_t)split * NHEADS + h) * NQ + gq] = l_run[r];
      }
    }
  }
}

__global__ __launch_bounds__(256) void attn_kernel(
    const __hip_bfloat16* __restrict__ Qp,
    const __hip_bfloat16* __restrict__ Kp,
    const __hip_bfloat16* __restrict__ Vt,
    const void* __restrict__ Wl,
    const int* __restrict__ vis,
    float* __restrict__ Opart, float* __restrict__ Mpart, float* __restrict__ Lpart,
    const int* __restrict__ flag)
{
  __shared__ alignas(16) __hip_bfloat16 lq[TQ * QSTR];
  __shared__ alignas(16) __hip_bfloat16 lk[TK * KSTR];
  __shared__ alignas(16) __hip_bfloat16 lv[128 * VSTR];
  __shared__ alignas(16) float2 lab[TQ * TK];
  __shared__ alignas(16) __hip_bfloat16 lp[NHEADS * TQ * PSTR];
  if (*flag)
    attn_body<float>(Qp, Kp, Vt, Wl, vis, Opart, Mpart, Lpart, lq, lk, lv, lab, lp);
  else
    attn_body<__hip_bfloat16>(Qp, Kp, Vt, Wl, vis, Opart, Mpart, Lpart, lq, lk, lv, lab, lp);
}

// ---------------- merge + proj + MLP ----------------
template<typename TI>
__device__ __forceinline__ void mlp_body(
    const float* __restrict__ Opart, const float* __restrict__ Mpart,
    const float* __restrict__ Lpart,
    const void* skip,
    const void* wproj, const void* bproj,
    const void* pre_g, const void* pre_b,
    const void* w1, const void* b1,
    const void* w2, const void* b2,
    const void* post_g, const void* post_b,
    void* out, float* sa, float* sz, float* sh, float* sred)
{
  const int t = threadIdx.x;
  const int q = blockIdx.x;
  const int hh = t >> 5;  // channel -> head

  float m0 = Mpart[(0 * NHEADS + hh) * NQ + q];
  float m1 = Mpart[(1 * NHEADS + hh) * NQ + q];
  float m2 = Mpart[(2 * NHEADS + hh) * NQ + q];
  float mm = fmaxf(m0, fmaxf(m1, m2));
  float e0 = __expf(m0 - mm), e1 = __expf(m1 - mm), e2 = __expf(m2 - mm);
  float ll = Lpart[(0 * NHEADS + hh) * NQ + q] * e0
           + Lpart[(1 * NHEADS + hh) * NQ + q] * e1
           + Lpart[(2 * NHEADS + hh) * NQ + q] * e2;
  float oo = Opart[(size_t)q * 128 + t] * e0
           + Opart[(size_t)NQ * 128 + (size_t)q * 128 + t] * e1
           + Opart[(size_t)2 * NQ * 128 + (size_t)q * 128 + t] * e2;
  sa[t] = oo / fmaxf(ll, 1e-30f);
  __syncthreads();

  float acc = LD<TI>::ld(bproj, t);
  #pragma unroll 8
  for (int d = 0; d < 128; ++d)
    acc += sa[d] * LD<TI>::ld(wproj, (size_t)t * 128 + d);

  float z = acc + LD<TI>::ld(skip, (size_t)t * NQ + q);
  float mean, rstd;
  ln_stats128(z, sred, mean, rstd);
  float zn = (z - mean) * rstd * LD<TI>::ld(pre_g, t) + LD<TI>::ld(pre_b, t);
  sz[t] = zn;
  __syncthreads();

  for (int o = t; o < 256; o += 128) {
    float a1 = LD<TI>::ld(b1, o);
    #pragma unroll 8
    for (int d = 0; d < 128; ++d)
      a1 += sz[d] * LD<TI>::ld(w1, (size_t)o * 128 + d);
    sh[o] = 0.5f * a1 * (1.0f + erff(a1 * 0.70710678118654752f));
  }
  __syncthreads();

  float a2 = LD<TI>::ld(b2, t);
  #pragma unroll 8
  for (int j = 0; j < 256; ++j)
    a2 += sh[j] * LD<TI>::ld(w2, (size_t)t * 256 + j);

  float y = zn + a2;
  float mean2, rstd2;
  ln_stats128(y, sred, mean2, rstd2);
  float yo = (y - mean2) * rstd2 * LD<TI>::ld(post_g, t) + LD<TI>::ld(post_b, t);
  if constexpr (sizeof(TI) == 4)
    ((float*)out)[(size_t)t * NQ + q] = yo;
  else
    ((__hip_bfloat16*)out)[(size_t)t * NQ + q] = __float2bfloat16(yo);
}

__global__ __launch_bounds__(128) void mlp_kernel(
    const float* __restrict__ Opart, const float* __restrict__ Mpart,
    const float* __restrict__ Lpart,
    const void* skip,
    const void* wproj, const void* bproj,
    const void* pre_g, const void* pre_b,
    const void* w1, const void* b1,
    const void* w2, const void* b2,
    const void* post_g, const void* post_b,
    void* out, const int* __restrict__ flag)
{
  __shared__ float sa[128];
  __shared__ float sz[128];
  __shared__ float sh[256];
  __shared__ float sred[4];
  if (*flag)
    mlp_body<float>(Opart, Mpart, Lpart, skip, wproj, bproj, pre_g, pre_b,
                    w1, b1, w2, b2, post_g, post_b, out, sa, sz, sh, sred);
  else
    mlp_body<__hip_bfloat16>(Opart, Mpart, Lpart, skip, wproj, bproj, pre_g, pre_b,
                             w1, b1, w2, b2, post_g, post_b, out, sa, sz, sh, sred);
}

extern "C" void kernel_launch(void* const* d_in, const int* in_sizes, int n_in,
                              void* d_out, int out_size, void* d_ws, size_t ws_size,
                              hipStream_t stream) {
  if (ws_size < (size_t)WS_REQ) return;  // diagnostic guard (output stays 0)

  const void* q     = d_in[0];
  const void* k     = d_in[1];
  const void* v     = d_in[2];
  const void* Wl    = d_in[3];
  const int*  vis   = (const int*)d_in[4];
  const void* skip  = d_in[5];
  const void* qn_g  = d_in[6];
  const void* qn_b  = d_in[7];
  const void* kn_g  = d_in[8];
  const void* kn_b  = d_in[9];
  const void* vn_g  = d_in[10];
  const void* vn_b  = d_in[11];
  const void* wq    = d_in[12];
  const void* bq    = d_in[13];
  const void* wk    = d_in[14];
  const void* bk    = d_in[15];
  const void* wv    = d_in[16];
  const void* bv    = d_in[17];
  const void* wproj = d_in[18];
  const void* bproj = d_in[19];
  const void* pre_g = d_in[20];
  const void* pre_b = d_in[21];
  const void* w1    = d_in[22];
  const void* b1    = d_in[23];
  const void* w2    = d_in[24];
  const void* b2    = d_in[25];
  const void* post_g= d_in[26];
  const void* post_b= d_in[27];

  char* ws = (char*)d_ws;
  __hip_bfloat16* Qp = (__hip_bfloat16*)(ws + WS_QP);
  __hip_bfloat16* Kp = (__hip_bfloat16*)(ws + WS_KP);
  __hip_bfloat16* Vt = (__hip_bfloat16*)(ws + WS_VT);
  float* Opart = (float*)(ws + WS_OP);
  float* Mpart = (float*)(ws + WS_MP);
  float* Lpart = (float*)(ws + WS_LP);
  int* flag = (int*)(ws + WS_FLAG);

  hipLaunchKernelGGL(probe_kernel, dim3(1), dim3(64), 0, stream,
                     (const unsigned*)qn_g, flag);

  hipLaunchKernelGGL(lnproj_kernel, dim3(NQ + 2 * NKK), dim3(128), 0, stream,
                     q, k, v, qn_g, qn_b, kn_g, kn_b, vn_g, vn_b,
                     wq, bq, wk, bk, wv, bv, Qp, Kp, Vt, flag);

  hipLaunchKernelGGL(attn_kernel, dim3(QBLOCKS, KSPLIT), dim3(256), 0, stream,
                     Qp, Kp, Vt, Wl, vis, Opart, Mpart, Lpart, flag);

  hipLaunchKernelGGL(mlp_kernel, dim3(NQ), dim3(128), 0, stream,
                     Opart, Mpart, Lpart, skip, wproj, bproj, pre_g, pre_b,
                     w1, b1, w2, b2, post_g, post_b, d_out, flag);
}

// Round 4
// 331.263 us; speedup vs baseline: 1.4544x; 1.4544x over previous
//
#include <hip/hip_runtime.h>
#include <hip/hip_bf16.h>

typedef __attribute__((ext_vector_type(8))) short bf16x8;
typedef __attribute__((ext_vector_type(4))) float f32x4;

#define NQ 2500
#define NKK 6336
#define NHEADS 4
#define DHEAD 32
#define SCALE 0.17677669529663687f
#define BIGNEG (-1.0e30f)

// workspace byte offsets (all 16B aligned)
#define WS_QP 0
#define WS_KP 640000
#define WS_VT 2262016
#define WS_OP 3884032
#define WS_MP 7724032
#define WS_LP 7844032
#define WS_REQ 7964032

#define KSPLIT 3
#define SPLIT_LEN 2112
#define TILES_PER_SPLIT 33
#define TQ 16
#define TK 64
#define QBLOCKS 157

#define QSTR 136
#define KSTR 136
#define VSTR 72
#define PSTR 72

__device__ __forceinline__ short bf16bits(float x) {
  union { __hip_bfloat16 h; short s; } cv;
  cv.h = __float2bfloat16(x);
  return cv.s;
}

// ================= lnproj: LN + 128x128 projection, MFMA =================
// 64 rows/block, 128 threads (2 waves). Blocks: q 40, k 99, v 99 = 238.
__global__ __launch_bounds__(128) void lnproj_kernel(
    const float* __restrict__ qin, const float* __restrict__ kin, const float* __restrict__ vin,
    const float* __restrict__ qn_g, const float* __restrict__ qn_b,
    const float* __restrict__ kn_g, const float* __restrict__ kn_b,
    const float* __restrict__ vn_g, const float* __restrict__ vn_b,
    const float* __restrict__ wq, const float* __restrict__ bq,
    const float* __restrict__ wk, const float* __restrict__ bk,
    const float* __restrict__ wv, const float* __restrict__ bv,
    __hip_bfloat16* __restrict__ Qp, __hip_bfloat16* __restrict__ Kp,
    __hip_bfloat16* __restrict__ Vt)
{
  __shared__ float lx[64][132];                 // raw fp32 X tile
  __shared__ __hip_bfloat16 lxb[64][136];       // normalized bf16 X tile
  __shared__ float lstat[64][2][2];
  __shared__ float lmr[64][2];
  __shared__ float lg[128], lbe[128], lbias[128];

  const int t = threadIdx.x;
  const int bb = blockIdx.x;
  int mode, row0;
  const float *in, *g, *be, *w, *bo;
  if (bb < 40)       { mode = 0; row0 = bb * 64;        in = qin; g = qn_g; be = qn_b; w = wq; bo = bq; }
  else if (bb < 139) { mode = 1; row0 = (bb - 40) * 64;  in = kin; g = kn_g; be = kn_b; w = wk; bo = bk; }
  else               { mode = 2; row0 = (bb - 139) * 64; in = vin; g = vn_g; be = vn_b; w = wv; bo = bv; }

  if (t < 128) { lg[t] = g[t]; lbe[t] = be[t]; lbias[t] = bo[t]; }

  const int row = t & 63, half = t >> 6;
  const int grow = row0 + row;
  size_t base; size_t dstr;
  bool rvalid = true;
  if (mode == 0) { rvalid = (grow < NQ); base = (size_t)(rvalid ? grow : NQ - 1); dstr = NQ; }
  else { int n = grow / 1056, rr = grow - n * 1056; base = (size_t)n * 135168 + rr; dstr = 1056; }

  float s = 0.f, ss = 0.f;
  for (int i = 0; i < 64; ++i) {
    int d = half * 64 + i;
    float x = rvalid ? in[base + (size_t)d * dstr] : 0.f;
    lx[row][d] = x;
    s += x; ss += x * x;
  }
  lstat[row][half][0] = s; lstat[row][half][1] = ss;
  __syncthreads();
  if (t < 64) {
    float S  = lstat[t][0][0] + lstat[t][1][0];
    float SS = lstat[t][0][1] + lstat[t][1][1];
    float mean = S * (1.f / 128.f);
    float var  = SS * (1.f / 128.f) - mean * mean;
    lmr[t][0] = mean;
    lmr[t][1] = rsqrtf(fmaxf(var, 0.f) + 1e-5f);
  }
  __syncthreads();
  {
    float mean = lmr[row][0], rstd = lmr[row][1];
    for (int i = 0; i < 64; ++i) {
      int d = half * 64 + i;
      float xn = (lx[row][d] - mean) * rstd * lg[d] + lbe[d];
      lxb[row][d] = __float2bfloat16(xn);
    }
  }
  __syncthreads();

  // GEMM: [64 rows] x [128 out], K=128. Wave covers 64-wide o-chunk.
  const int lane = t & 63;
  const int n16 = lane & 15, quad = lane >> 4;
  const int o0 = (t >> 6) * 64;

  f32x4 acc[4][4] = {};
  for (int kt = 0; kt < 4; ++kt) {
    bf16x8 af[4];
    #pragma unroll
    for (int mi = 0; mi < 4; ++mi)
      af[mi] = *(const bf16x8*)&lxb[mi * 16 + n16][kt * 32 + quad * 8];
    #pragma unroll
    for (int ni = 0; ni < 4; ++ni) {
      int o = o0 + ni * 16 + n16;
      const float* wp = w + (size_t)o * 128 + kt * 32 + quad * 8;
      bf16x8 bfv;
      #pragma unroll
      for (int j = 0; j < 8; ++j) bfv[j] = bf16bits(wp[j]);
      #pragma unroll
      for (int mi = 0; mi < 4; ++mi)
        acc[mi][ni] = __builtin_amdgcn_mfma_f32_16x16x32_bf16(af[mi], bfv, acc[mi][ni], 0, 0, 0);
    }
  }

  #pragma unroll
  for (int mi = 0; mi < 4; ++mi) {
    #pragma unroll
    for (int rg = 0; rg < 4; ++rg) {
      int r = mi * 16 + quad * 4 + rg;
      int gr = row0 + r;
      if (mode != 0 || gr < NQ) {
        #pragma unroll
        for (int ni = 0; ni < 4; ++ni) {
          int o = o0 + ni * 16 + n16;
          __hip_bfloat16 b16 = __float2bfloat16(acc[mi][ni][rg] + lbias[o]);
          if (mode == 0)      Qp[(size_t)gr * 128 + o] = b16;
          else if (mode == 1) Kp[(size_t)gr * 128 + o] = b16;
          else                Vt[(size_t)o * NKK + gr] = b16;
        }
      }
    }
  }
}

// ================= attention (unchanged structure, fp32 inputs) =================
__global__ __launch_bounds__(256) void attn_kernel(
    const __hip_bfloat16* __restrict__ Qp,
    const __hip_bfloat16* __restrict__ Kp,
    const __hip_bfloat16* __restrict__ Vt,
    const float* __restrict__ Wl,
    const int* __restrict__ vis,
    float* __restrict__ Opart, float* __restrict__ Mpart, float* __restrict__ Lpart)
{
  __shared__ alignas(16) __hip_bfloat16 lq[TQ * QSTR];
  __shared__ alignas(16) __hip_bfloat16 lk[TK * KSTR];
  __shared__ alignas(16) __hip_bfloat16 lv[128 * VSTR];
  __shared__ alignas(16) float2 lab[TQ * TK];
  __shared__ alignas(16) __hip_bfloat16 lp[NHEADS * TQ * PSTR];

  const int t = threadIdx.x;
  const int lane = t & 63;
  const int h = t >> 6;
  const int n16 = lane & 15;
  const int quad = lane >> 4;
  const int q0 = blockIdx.x * TQ;
  const int split = blockIdx.y;
  const int kbase = split * SPLIT_LEN;

  {
    int e = t * 8;
    int r = e >> 7, c = e & 127;
    int gq = q0 + r;
    uint4 val = make_uint4(0u, 0u, 0u, 0u);
    if (gq < NQ) val = *(const uint4*)(Qp + (size_t)gq * 128 + c);
    *(uint4*)&lq[r * QSTR + c] = val;
  }
  __syncthreads();

  bf16x8 aq = *(const bf16x8*)&lq[n16 * QSTR + h * DHEAD + quad * 8];

  f32x4 o0 = {0.f, 0.f, 0.f, 0.f};
  f32x4 o1 = {0.f, 0.f, 0.f, 0.f};
  float m_run[4], l_run[4];
  #pragma unroll
  for (int r = 0; r < 4; ++r) { m_run[r] = BIGNEG; l_run[r] = 0.f; }

  for (int kt = 0; kt < TILES_PER_SPLIT; ++kt) {
    const int k0 = kbase + kt * TK;
    {
      int r = t >> 2, c0 = (t & 3) * 32;
      const uint4* src = (const uint4*)(Kp + (size_t)(k0 + r) * 128 + c0);
      uint4* dst = (uint4*)&lk[r * KSTR + c0];
      #pragma unroll
      for (int i = 0; i < 4; ++i) dst[i] = src[i];
    }
    {
      int r = t >> 1, c0 = (t & 1) * 32;
      const uint4* src = (const uint4*)(Vt + (size_t)r * NKK + k0 + c0);
      uint4* dst = (uint4*)&lv[r * VSTR + c0];
      #pragma unroll
      for (int i = 0; i < 4; ++i) dst[i] = src[i];
    }
    {
      int e = t * 4;
      int qq = e >> 6, kk = e & 63;
      int gq = q0 + qq; if (gq > NQ - 1) gq = NQ - 1;
      size_t bidx = (size_t)gq * NKK + k0 + kk;
      float4 w4 = *(const float4*)(Wl + bidx);
      int4 v4 = *(const int4*)(vis + bidx);
      float wf[4] = {w4.x, w4.y, w4.z, w4.w};
      int vv[4] = {v4.x, v4.y, v4.z, v4.w};
      #pragma unroll
      for (int j = 0; j < 4; ++j) {
        float a = vv[j] ? wf[j] * SCALE : 0.f;
        float b = vv[j] ? 0.f : BIGNEG * wf[j];
        lab[e + j] = make_float2(a, b);
      }
    }
    __syncthreads();

    f32x4 s[4];
    #pragma unroll
    for (int ks = 0; ks < 4; ++ks) {
      bf16x8 bk = *(const bf16x8*)&lk[(ks * 16 + n16) * KSTR + h * DHEAD + quad * 8];
      f32x4 z = {0.f, 0.f, 0.f, 0.f};
      s[ks] = __builtin_amdgcn_mfma_f32_16x16x32_bf16(aq, bk, z, 0, 0, 0);
    }

    float lvv[4][4];
    #pragma unroll
    for (int ks = 0; ks < 4; ++ks) {
      #pragma unroll
      for (int r = 0; r < 4; ++r) {
        float2 ab = lab[(quad * 4 + r) * TK + ks * 16 + n16];
        lvv[ks][r] = s[ks][r] * ab.x + ab.y;
      }
    }
    float alpha[4];
    #pragma unroll
    for (int r = 0; r < 4; ++r) {
      float tm = fmaxf(fmaxf(lvv[0][r], lvv[1][r]), fmaxf(lvv[2][r], lvv[3][r]));
      tm = fmaxf(tm, __shfl_xor(tm, 1));
      tm = fmaxf(tm, __shfl_xor(tm, 2));
      tm = fmaxf(tm, __shfl_xor(tm, 4));
      tm = fmaxf(tm, __shfl_xor(tm, 8));
      float m_new = fmaxf(m_run[r], tm);
      alpha[r] = __expf(m_run[r] - m_new);
      m_run[r] = m_new;
      float ssum = 0.f;
      #pragma unroll
      for (int ks = 0; ks < 4; ++ks) {
        float p = __expf(fmaxf(lvv[ks][r] - m_new, BIGNEG));
        lvv[ks][r] = p;
        ssum += p;
      }
      ssum += __shfl_xor(ssum, 1);
      ssum += __shfl_xor(ssum, 2);
      ssum += __shfl_xor(ssum, 4);
      ssum += __shfl_xor(ssum, 8);
      l_run[r] = l_run[r] * alpha[r] + ssum;
    }
    #pragma unroll
    for (int ks = 0; ks < 4; ++ks) {
      #pragma unroll
      for (int r = 0; r < 4; ++r)
        lp[h * (TQ * PSTR) + (quad * 4 + r) * PSTR + ks * 16 + n16] = __float2bfloat16(lvv[ks][r]);
    }
    #pragma unroll
    for (int r = 0; r < 4; ++r) { o0[r] *= alpha[r]; o1[r] *= alpha[r]; }

    #pragma unroll
    for (int kk = 0; kk < 2; ++kk) {
      bf16x8 ap  = *(const bf16x8*)&lp[h * (TQ * PSTR) + n16 * PSTR + kk * 32 + quad * 8];
      bf16x8 bv0 = *(const bf16x8*)&lv[(h * DHEAD + n16) * VSTR + kk * 32 + quad * 8];
      bf16x8 bv1 = *(const bf16x8*)&lv[(h * DHEAD + 16 + n16) * VSTR + kk * 32 + quad * 8];
      o0 = __builtin_amdgcn_mfma_f32_16x16x32_bf16(ap, bv0, o0, 0, 0, 0);
      o1 = __builtin_amdgcn_mfma_f32_16x16x32_bf16(ap, bv1, o1, 0, 0, 0);
    }
    __syncthreads();
  }

  #pragma unroll
  for (int r = 0; r < 4; ++r) {
    int gq = q0 + quad * 4 + r;
    if (gq < NQ) {
      size_t ob = (size_t)split * (NQ * 128) + (size_t)gq * 128 + h * DHEAD;
      Opart[ob + n16] = o0[r];
      Opart[ob + 16 + n16] = o1[r];
      if (n16 == 0) {
        Mpart[((size_t)split * NHEADS + h) * NQ + gq] = m_run[r];
        Lpart[((size_t)split * NHEADS + h) * NQ + gq] = l_run[r];
      }
    }
  }
}

// ================= merge + proj + preLN + MLP + postLN, MFMA =================
// 32 queries/block, 256 threads (4 waves). 79 blocks.
__global__ __launch_bounds__(256) void mlp_kernel(
    const float* __restrict__ Opart, const float* __restrict__ Mpart,
    const float* __restrict__ Lpart,
    const float* __restrict__ skip,
    const float* __restrict__ wproj, const float* __restrict__ bproj,
    const float* __restrict__ pre_g, const float* __restrict__ pre_b,
    const float* __restrict__ w1, const float* __restrict__ b1,
    const float* __restrict__ w2, const float* __restrict__ b2,
    const float* __restrict__ post_g, const float* __restrict__ post_b,
    float* __restrict__ out)
{
  __shared__ __hip_bfloat16 sab[32][136];  // merged attention out (bf16 A-tile)
  __shared__ __hip_bfloat16 znb[32][136];  // preLN out bf16 (A for GEMM2)
  __shared__ float znf[32][132];           // preLN out fp32 (residual)
  __shared__ __hip_bfloat16 hb[32][264];   // hidden bf16 (A for GEMM3)
  __shared__ float part[32][4][2];

  const int t = threadIdx.x;
  const int q0 = blockIdx.x * 32;

  // ---- merge k-splits ----
  {
    int row = t >> 3, c0 = (t & 7) * 16;
    int gq = q0 + row; int cq = gq < NQ ? gq : NQ - 1;
    int head = c0 >> 5;
    float m0 = Mpart[(0 * NHEADS + head) * NQ + cq];
    float m1 = Mpart[(1 * NHEADS + head) * NQ + cq];
    float m2 = Mpart[(2 * NHEADS + head) * NQ + cq];
    float mm = fmaxf(m0, fmaxf(m1, m2));
    float e0 = __expf(m0 - mm), e1 = __expf(m1 - mm), e2 = __expf(m2 - mm);
    float ll = Lpart[(0 * NHEADS + head) * NQ + cq] * e0
             + Lpart[(1 * NHEADS + head) * NQ + cq] * e1
             + Lpart[(2 * NHEADS + head) * NQ + cq] * e2;
    float rll = 1.f / fmaxf(ll, 1e-30f);
    const float* p0 = Opart + (size_t)cq * 128 + c0;
    const float* p1 = p0 + (size_t)NQ * 128;
    const float* p2 = p1 + (size_t)NQ * 128;
    #pragma unroll
    for (int i = 0; i < 16; i += 4) {
      float4 a = *(const float4*)(p0 + i);
      float4 b = *(const float4*)(p1 + i);
      float4 c = *(const float4*)(p2 + i);
      sab[row][c0 + i + 0] = __float2bfloat16((a.x * e0 + b.x * e1 + c.x * e2) * rll);
      sab[row][c0 + i + 1] = __float2bfloat16((a.y * e0 + b.y * e1 + c.y * e2) * rll);
      sab[row][c0 + i + 2] = __float2bfloat16((a.z * e0 + b.z * e1 + c.z * e2) * rll);
      sab[row][c0 + i + 3] = __float2bfloat16((a.w * e0 + b.w * e1 + c.w * e2) * rll);
    }
  }
  __syncthreads();

  const int wid = t >> 6, lane = t & 63;
  const int n16 = lane & 15, quad = lane >> 4;

  // ---- GEMM1: proj (N=128), wave covers 32-wide o-chunk ----
  f32x4 acc1[2][2] = {};
  for (int kt = 0; kt < 4; ++kt) {
    bf16x8 af[2];
    #pragma unroll
    for (int mi = 0; mi < 2; ++mi)
      af[mi] = *(const bf16x8*)&sab[mi * 16 + n16][kt * 32 + quad * 8];
    #pragma unroll
    for (int ni = 0; ni < 2; ++ni) {
      int o = wid * 32 + ni * 16 + n16;
      const float* wp = wproj + (size_t)o * 128 + kt * 32 + quad * 8;
      bf16x8 bfv;
      #pragma unroll
      for (int j = 0; j < 8; ++j) bfv[j] = bf16bits(wp[j]);
      #pragma unroll
      for (int mi = 0; mi < 2; ++mi)
        acc1[mi][ni] = __builtin_amdgcn_mfma_f32_16x16x32_bf16(af[mi], bfv, acc1[mi][ni], 0, 0, 0);
    }
  }
  // z = acc1 + bproj + skip ; then block LN
  float z[2][2][4];
  #pragma unroll
  for (int mi = 0; mi < 2; ++mi) {
    #pragma unroll
    for (int ni = 0; ni < 2; ++ni) {
      int o = wid * 32 + ni * 16 + n16;
      float bo = bproj[o];
      int qb = q0 + mi * 16 + quad * 4;
      if (qb + 3 < NQ) {
        float4 sk = *(const float4*)(skip + (size_t)o * NQ + qb);
        z[mi][ni][0] = acc1[mi][ni][0] + bo + sk.x;
        z[mi][ni][1] = acc1[mi][ni][1] + bo + sk.y;
        z[mi][ni][2] = acc1[mi][ni][2] + bo + sk.z;
        z[mi][ni][3] = acc1[mi][ni][3] + bo + sk.w;
      } else {
        #pragma unroll
        for (int rg = 0; rg < 4; ++rg) {
          int cq = qb + rg < NQ ? qb + rg : NQ - 1;
          z[mi][ni][rg] = acc1[mi][ni][rg] + bo + skip[(size_t)o * NQ + cq];
        }
      }
    }
  }
  #pragma unroll
  for (int mi = 0; mi < 2; ++mi) {
    #pragma unroll
    for (int rg = 0; rg < 4; ++rg) {
      float s = z[mi][0][rg] + z[mi][1][rg];
      float ss = z[mi][0][rg] * z[mi][0][rg] + z[mi][1][rg] * z[mi][1][rg];
      s  += __shfl_xor(s, 1);  ss += __shfl_xor(ss, 1);
      s  += __shfl_xor(s, 2);  ss += __shfl_xor(ss, 2);
      s  += __shfl_xor(s, 4);  ss += __shfl_xor(ss, 4);
      s  += __shfl_xor(s, 8);  ss += __shfl_xor(ss, 8);
      if (n16 == 0) { part[mi * 16 + quad * 4 + rg][wid][0] = s; part[mi * 16 + quad * 4 + rg][wid][1] = ss; }
    }
  }
  __syncthreads();
  #pragma unroll
  for (int mi = 0; mi < 2; ++mi) {
    #pragma unroll
    for (int rg = 0; rg < 4; ++rg) {
      int row = mi * 16 + quad * 4 + rg;
      float S  = part[row][0][0] + part[row][1][0] + part[row][2][0] + part[row][3][0];
      float SS = part[row][0][1] + part[row][1][1] + part[row][2][1] + part[row][3][1];
      float mean = S * (1.f / 128.f);
      float var  = SS * (1.f / 128.f) - mean * mean;
      float rstd = rsqrtf(fmaxf(var, 0.f) + 1e-5f);
      #pragma unroll
      for (int ni = 0; ni < 2; ++ni) {
        int o = wid * 32 + ni * 16 + n16;
        float zn = (z[mi][ni][rg] - mean) * rstd * pre_g[o] + pre_b[o];
        znf[row][o] = zn;
        znb[row][o] = __float2bfloat16(zn);
      }
    }
  }
  __syncthreads();

  // ---- GEMM2: 128 -> 256 + GELU ----
  f32x4 acc2[2][4] = {};
  for (int kt = 0; kt < 4; ++kt) {
    bf16x8 af[2];
    #pragma unroll
    for (int mi = 0; mi < 2; ++mi)
      af[mi] = *(const bf16x8*)&znb[mi * 16 + n16][kt * 32 + quad * 8];
    #pragma unroll
    for (int ni = 0; ni < 4; ++ni) {
      int j = wid * 64 + ni * 16 + n16;
      const float* wp = w1 + (size_t)j * 128 + kt * 32 + quad * 8;
      bf16x8 bfv;
      #pragma unroll
      for (int jj = 0; jj < 8; ++jj) bfv[jj] = bf16bits(wp[jj]);
      #pragma unroll
      for (int mi = 0; mi < 2; ++mi)
        acc2[mi][ni] = __builtin_amdgcn_mfma_f32_16x16x32_bf16(af[mi], bfv, acc2[mi][ni], 0, 0, 0);
    }
  }
  #pragma unroll
  for (int mi = 0; mi < 2; ++mi) {
    #pragma unroll
    for (int ni = 0; ni < 4; ++ni) {
      int j = wid * 64 + ni * 16 + n16;
      float bj = b1[j];
      #pragma unroll
      for (int rg = 0; rg < 4; ++rg) {
        int row = mi * 16 + quad * 4 + rg;
        float a1 = acc2[mi][ni][rg] + bj;
        float hgelu = 0.5f * a1 * (1.0f + erff(a1 * 0.70710678118654752f));
        hb[row][j] = __float2bfloat16(hgelu);
      }
    }
  }
  __syncthreads();

  // ---- GEMM3: 256 -> 128 + residual + postLN ----
  f32x4 acc3[2][2] = {};
  for (int kt = 0; kt < 8; ++kt) {
    bf16x8 af[2];
    #pragma unroll
    for (int mi = 0; mi < 2; ++mi)
      af[mi] = *(const bf16x8*)&hb[mi * 16 + n16][kt * 32 + quad * 8];
    #pragma unroll
    for (int ni = 0; ni < 2; ++ni) {
      int o = wid * 32 + ni * 16 + n16;
      const float* wp = w2 + (size_t)o * 256 + kt * 32 + quad * 8;
      bf16x8 bfv;
      #pragma unroll
      for (int j = 0; j < 8; ++j) bfv[j] = bf16bits(wp[j]);
      #pragma unroll
      for (int mi = 0; mi < 2; ++mi)
        acc3[mi][ni] = __builtin_amdgcn_mfma_f32_16x16x32_bf16(af[mi], bfv, acc3[mi][ni], 0, 0, 0);
    }
  }
  float y[2][2][4];
  #pragma unroll
  for (int mi = 0; mi < 2; ++mi) {
    #pragma unroll
    for (int ni = 0; ni < 2; ++ni) {
      int o = wid * 32 + ni * 16 + n16;
      float bo = b2[o];
      #pragma unroll
      for (int rg = 0; rg < 4; ++rg) {
        int row = mi * 16 + quad * 4 + rg;
        y[mi][ni][rg] = znf[row][o] + acc3[mi][ni][rg] + bo;
      }
    }
  }
  #pragma unroll
  for (int mi = 0; mi < 2; ++mi) {
    #pragma unroll
    for (int rg = 0; rg < 4; ++rg) {
      float s = y[mi][0][rg] + y[mi][1][rg];
      float ss = y[mi][0][rg] * y[mi][0][rg] + y[mi][1][rg] * y[mi][1][rg];
      s  += __shfl_xor(s, 1);  ss += __shfl_xor(ss, 1);
      s  += __shfl_xor(s, 2);  ss += __shfl_xor(ss, 2);
      s  += __shfl_xor(s, 4);  ss += __shfl_xor(ss, 4);
      s  += __shfl_xor(s, 8);  ss += __shfl_xor(ss, 8);
      if (n16 == 0) { part[mi * 16 + quad * 4 + rg][wid][0] = s; part[mi * 16 + quad * 4 + rg][wid][1] = ss; }
    }
  }
  __syncthreads();
  #pragma unroll
  for (int mi = 0; mi < 2; ++mi) {
    #pragma unroll
    for (int rg = 0; rg < 4; ++rg) {
      int row = mi * 16 + quad * 4 + rg;
      float S  = part[row][0][0] + part[row][1][0] + part[row][2][0] + part[row][3][0];
      float SS = part[row][0][1] + part[row][1][1] + part[row][2][1] + part[row][3][1];
      float mean = S * (1.f / 128.f);
      float var  = SS * (1.f / 128.f) - mean * mean;
      float rstd = rsqrtf(fmaxf(var, 0.f) + 1e-5f);
      #pragma unroll
      for (int ni = 0; ni < 2; ++ni) {
        int o = wid * 32 + ni * 16 + n16;
        y[mi][ni][rg] = (y[mi][ni][rg] - mean) * rstd * post_g[o] + post_b[o];
      }
    }
  }
  // store: out[o][q], 4 consecutive q per (mi,ni) -> float4
  #pragma unroll
  for (int mi = 0; mi < 2; ++mi) {
    #pragma unroll
    for (int ni = 0; ni < 2; ++ni) {
      int o = wid * 32 + ni * 16 + n16;
      int qb = q0 + mi * 16 + quad * 4;
      if (qb + 3 < NQ) {
        float4 v4 = make_float4(y[mi][ni][0], y[mi][ni][1], y[mi][ni][2], y[mi][ni][3]);
        *(float4*)(out + (size_t)o * NQ + qb) = v4;
      } else {
        #pragma unroll
        for (int rg = 0; rg < 4; ++rg)
          if (qb + rg < NQ) out[(size_t)o * NQ + qb + rg] = y[mi][ni][rg];
      }
    }
  }
}

extern "C" void kernel_launch(void* const* d_in, const int* in_sizes, int n_in,
                              void* d_out, int out_size, void* d_ws, size_t ws_size,
                              hipStream_t stream) {
  if (ws_size < (size_t)WS_REQ) return;

  const float* q     = (const float*)d_in[0];
  const float* k     = (const float*)d_in[1];
  const float* v     = (const float*)d_in[2];
  const float* Wl    = (const float*)d_in[3];
  const int*   vis   = (const int*)d_in[4];
  const float* skip  = (const float*)d_in[5];
  const float* qn_g  = (const float*)d_in[6];
  const float* qn_b  = (const float*)d_in[7];
  const float* kn_g  = (const float*)d_in[8];
  const float* kn_b  = (const float*)d_in[9];
  const float* vn_g  = (const float*)d_in[10];
  const float* vn_b  = (const float*)d_in[11];
  const float* wq    = (const float*)d_in[12];
  const float* bq    = (const float*)d_in[13];
  const float* wk    = (const float*)d_in[14];
  const float* bk    = (const float*)d_in[15];
  const float* wv    = (const float*)d_in[16];
  const float* bv    = (const float*)d_in[17];
  const float* wproj = (const float*)d_in[18];
  const float* bproj = (const float*)d_in[19];
  const float* pre_g = (const float*)d_in[20];
  const float* pre_b = (const float*)d_in[21];
  const float* w1    = (const float*)d_in[22];
  const float* b1    = (const float*)d_in[23];
  const float* w2    = (const float*)d_in[24];
  const float* b2    = (const float*)d_in[25];
  const float* post_g= (const float*)d_in[26];
  const float* post_b= (const float*)d_in[27];

  char* ws = (char*)d_ws;
  __hip_bfloat16* Qp = (__hip_bfloat16*)(ws + WS_QP);
  __hip_bfloat16* Kp = (__hip_bfloat16*)(ws + WS_KP);
  __hip_bfloat16* Vt = (__hip_bfloat16*)(ws + WS_VT);
  float* Opart = (float*)(ws + WS_OP);
  float* Mpart = (float*)(ws + WS_MP);
  float* Lpart = (float*)(ws + WS_LP);

  hipLaunchKernelGGL(lnproj_kernel, dim3(238), dim3(128), 0, stream,
                     q, k, v, qn_g, qn_b, kn_g, kn_b, vn_g, vn_b,
                     wq, bq, wk, bk, wv, bv, Qp, Kp, Vt);

  hipLaunchKernelGGL(attn_kernel, dim3(QBLOCKS, KSPLIT), dim3(256), 0, stream,
                     Qp, Kp, Vt, Wl, vis, Opart, Mpart, Lpart);

  hipLaunchKernelGGL(mlp_kernel, dim3(79), dim3(256), 0, stream,
                     Opart, Mpart, Lpart, skip, wproj, bproj, pre_g, pre_b,
                     w1, b1, w2, b2, post_g, post_b, (float*)d_out);
}

// Round 5
// 261.598 us; speedup vs baseline: 1.8418x; 1.2663x over previous
//
#include <hip/hip_runtime.h>
#include <hip/hip_bf16.h>

typedef __attribute__((ext_vector_type(8))) short bf16x8;
typedef __attribute__((ext_vector_type(4))) float f32x4;

#define NQ 2500
#define NKK 6336
#define NHEADS 4
#define DHEAD 32
#define SCALE 0.17677669529663687f
#define BIGNEG (-1.0e30f)

// workspace byte offsets (all 16B aligned)
#define WS_QP 0
#define WS_KP 640000
#define WS_VT 2262016
#define WS_OP 3884032
#define WS_MP 7724032
#define WS_LP 7844032
#define WS_WB 7964032
#define WS_REQ 8226176

// bf16 weight element offsets inside WS_WB
#define WQB 0
#define WKB 16384
#define WVB 32768
#define WPROJB 49152
#define W1B 65536
#define W2B 98304

#define KSPLIT 3
#define SPLIT_LEN 2112
#define TILES_PER_SPLIT 33
#define TQ 16
#define TK 64
#define QBLOCKS 157

#define KSTR 136
#define VSTR 72
#define PSTR 72
#define ABSTR 68

__device__ __forceinline__ unsigned short bf16bits(float x) {
  union { __hip_bfloat16 h; unsigned short s; } cv;
  cv.h = __float2bfloat16(x);
  return cv.s;
}

// ============ weight fp32->bf16 conversion (once per launch) ============
__global__ __launch_bounds__(256) void wconv_kernel(
    const float* __restrict__ wq, const float* __restrict__ wk,
    const float* __restrict__ wv, const float* __restrict__ wproj,
    const float* __restrict__ w1, const float* __restrict__ w2,
    __hip_bfloat16* __restrict__ wb)
{
  int e = (blockIdx.x * 256 + threadIdx.x) * 4;
  const float* src; int off;
  if (e < 16384)      { src = wq;    off = e; }
  else if (e < 32768) { src = wk;    off = e - 16384; }
  else if (e < 49152) { src = wv;    off = e - 32768; }
  else if (e < 65536) { src = wproj; off = e - 49152; }
  else if (e < 98304) { src = w1;    off = e - 65536; }
  else                { src = w2;    off = e - 98304; }
  float4 v = *(const float4*)(src + off);
  ushort4 o4;
  o4.x = bf16bits(v.x); o4.y = bf16bits(v.y); o4.z = bf16bits(v.z); o4.w = bf16bits(v.w);
  *(ushort4*)((unsigned short*)wb + e) = o4;
}

// ============ lnproj: LN + 128x128 projection (MFMA), 32 rows/block ============
// blocks: q 79, k 198, v 198 = 475
__global__ __launch_bounds__(128) void lnproj_kernel(
    const float* __restrict__ qin, const float* __restrict__ kin, const float* __restrict__ vin,
    const float* __restrict__ qn_g, const float* __restrict__ qn_b,
    const float* __restrict__ kn_g, const float* __restrict__ kn_b,
    const float* __restrict__ vn_g, const float* __restrict__ vn_b,
    const __hip_bfloat16* __restrict__ wball,
    const float* __restrict__ bq, const float* __restrict__ bk, const float* __restrict__ bv,
    __hip_bfloat16* __restrict__ Qp, __hip_bfloat16* __restrict__ Kp,
    __hip_bfloat16* __restrict__ Vt)
{
  __shared__ __hip_bfloat16 lxb[32][136];
  __shared__ float lpart[32][4][2];
  __shared__ float lmr[32][2];
  __shared__ float lgb[128], lbeb[128];

  const int t = threadIdx.x;
  const int bb = blockIdx.x;
  int mode, row0;
  const float *in, *g, *be, *bo;
  const __hip_bfloat16* wb;
  if (bb < 79)       { mode = 0; row0 = bb * 32;         in = qin; g = qn_g; be = qn_b; wb = wball + WQB; bo = bq; }
  else if (bb < 277) { mode = 1; row0 = (bb - 79) * 32;  in = kin; g = kn_g; be = kn_b; wb = wball + WKB; bo = bk; }
  else               { mode = 2; row0 = (bb - 277) * 32; in = vin; g = vn_g; be = vn_b; wb = wball + WVB; bo = bv; }

  if (t < 128) { lgb[t] = g[t]; lbeb[t] = be[t]; }

  const int row = t & 31, seg = t >> 5;
  int grow = row0 + row;
  size_t base, dstr;
  bool rvalid = true;
  if (mode == 0) { rvalid = (grow < NQ); base = (size_t)(rvalid ? grow : NQ - 1); dstr = NQ; }
  else { int n = grow / 1056, rr = grow - n * 1056; base = (size_t)n * 135168 + rr; dstr = 1056; }

  float xr[32];
  float s = 0.f, ss = 0.f;
  #pragma unroll
  for (int i = 0; i < 32; ++i) {
    float x = in[base + (size_t)(seg * 32 + i) * dstr];
    xr[i] = x; s += x; ss += x * x;
  }
  lpart[row][seg][0] = s; lpart[row][seg][1] = ss;
  __syncthreads();
  if (t < 32) {
    float S  = lpart[t][0][0] + lpart[t][1][0] + lpart[t][2][0] + lpart[t][3][0];
    float SS = lpart[t][0][1] + lpart[t][1][1] + lpart[t][2][1] + lpart[t][3][1];
    float mean = S * (1.f / 128.f);
    float var  = SS * (1.f / 128.f) - mean * mean;
    lmr[t][0] = mean;
    lmr[t][1] = rsqrtf(fmaxf(var, 0.f) + 1e-5f);
  }
  __syncthreads();
  {
    float mean = lmr[row][0], rstd = lmr[row][1];
    #pragma unroll
    for (int i = 0; i < 32; ++i) {
      int d = seg * 32 + i;
      lxb[row][d] = __float2bfloat16((xr[i] - mean) * rstd * lgb[d] + lbeb[d]);
    }
  }
  __syncthreads();

  // GEMM: 32 rows x 128 out, K=128; 2 waves, each 64-wide o-chunk
  const int lane = t & 63;
  const int n16 = lane & 15, quad = lane >> 4;
  const int o0 = (t >> 6) * 64;

  f32x4 acc[2][4] = {};
  for (int kt = 0; kt < 4; ++kt) {
    bf16x8 af[2];
    #pragma unroll
    for (int mi = 0; mi < 2; ++mi)
      af[mi] = *(const bf16x8*)&lxb[mi * 16 + n16][kt * 32 + quad * 8];
    #pragma unroll
    for (int ni = 0; ni < 4; ++ni) {
      bf16x8 bw = *(const bf16x8*)(wb + (size_t)(o0 + ni * 16 + n16) * 128 + kt * 32 + quad * 8);
      #pragma unroll
      for (int mi = 0; mi < 2; ++mi)
        acc[mi][ni] = __builtin_amdgcn_mfma_f32_16x16x32_bf16(af[mi], bw, acc[mi][ni], 0, 0, 0);
    }
  }

  float bias[4];
  #pragma unroll
  for (int ni = 0; ni < 4; ++ni) bias[ni] = bo[o0 + ni * 16 + n16];

  #pragma unroll
  for (int mi = 0; mi < 2; ++mi) {
    int gr0 = row0 + mi * 16 + quad * 4;
    if (mode == 2) {
      // Vt transposed: 4 consecutive gr per (ni) -> 8B store
      #pragma unroll
      for (int ni = 0; ni < 4; ++ni) {
        int o = o0 + ni * 16 + n16;
        ushort4 v4;
        v4.x = bf16bits(acc[mi][ni][0] + bias[ni]);
        v4.y = bf16bits(acc[mi][ni][1] + bias[ni]);
        v4.z = bf16bits(acc[mi][ni][2] + bias[ni]);
        v4.w = bf16bits(acc[mi][ni][3] + bias[ni]);
        *(ushort4*)((unsigned short*)Vt + (size_t)o * NKK + gr0) = v4;
      }
    } else {
      #pragma unroll
      for (int rg = 0; rg < 4; ++rg) {
        int gr = gr0 + rg;
        if (mode != 0 || gr < NQ) {
          #pragma unroll
          for (int ni = 0; ni < 4; ++ni) {
            int o = o0 + ni * 16 + n16;
            __hip_bfloat16 b16 = __float2bfloat16(acc[mi][ni][rg] + bias[ni]);
            if (mode == 0) Qp[(size_t)gr * 128 + o] = b16;
            else           Kp[(size_t)gr * 128 + o] = b16;
          }
        }
      }
    }
  }
}

// ============ flash attention: software-pipelined, 3 blocks/CU ============
__global__ __launch_bounds__(256, 3) void attn_kernel(
    const __hip_bfloat16* __restrict__ Qp,
    const __hip_bfloat16* __restrict__ Kp,
    const __hip_bfloat16* __restrict__ Vt,
    const float* __restrict__ Wl,
    const int* __restrict__ vis,
    float* __restrict__ Opart, float* __restrict__ Mpart, float* __restrict__ Lpart)
{
  __shared__ alignas(16) __hip_bfloat16 lk[TK * KSTR];        // 17408 B
  __shared__ alignas(16) __hip_bfloat16 lv[128 * VSTR];       // 18432 B
  __shared__ alignas(16) float sa_[TQ * ABSTR];               // 4352 B
  __shared__ alignas(16) float sb_[TQ * ABSTR];               // 4352 B
  __shared__ alignas(16) __hip_bfloat16 lp[NHEADS * TQ * PSTR]; // 9216 B

  const int t = threadIdx.x;
  const int lane = t & 63;
  const int h = t >> 6;
  const int n16 = lane & 15;
  const int quad = lane >> 4;
  const int q0 = blockIdx.x * TQ;
  const int split = blockIdx.y;
  const int kbase = split * SPLIT_LEN;

  // Q A-fragment straight from global (no LDS tile needed)
  int gqa = q0 + n16; if (gqa >= NQ) gqa = NQ - 1;
  bf16x8 aq = *(const bf16x8*)(Qp + (size_t)gqa * 128 + h * DHEAD + quad * 8);

  // prefetch-coordinate precompute
  const int kr = t >> 2, kc = (t & 3) * 32;
  const int vr = t >> 1, vc = (t & 1) * 32;
  const int e4 = t * 4, qq = e4 >> 6, kkc = e4 & 63;
  int gqe = q0 + qq; if (gqe >= NQ) gqe = NQ - 1;
  const size_t wbase = (size_t)gqe * NKK + kkc;

  uint4 pk0, pk1, pk2, pk3, pv0, pv1, pv2, pv3;
  float4 pw; int4 pvs;

  auto issue = [&](int k0) {
    const uint4* ksrc = (const uint4*)(Kp + (size_t)(k0 + kr) * 128 + kc);
    pk0 = ksrc[0]; pk1 = ksrc[1]; pk2 = ksrc[2]; pk3 = ksrc[3];
    const uint4* vsrc = (const uint4*)(Vt + (size_t)vr * NKK + k0 + vc);
    pv0 = vsrc[0]; pv1 = vsrc[1]; pv2 = vsrc[2]; pv3 = vsrc[3];
    pw  = *(const float4*)(Wl + wbase + k0);
    pvs = *(const int4*)(vis + wbase + k0);
  };
  auto commit = [&]() {
    uint4* kd = (uint4*)&lk[kr * KSTR + kc];
    kd[0] = pk0; kd[1] = pk1; kd[2] = pk2; kd[3] = pk3;
    uint4* vd = (uint4*)&lv[vr * VSTR + vc];
    vd[0] = pv0; vd[1] = pv1; vd[2] = pv2; vd[3] = pv3;
    float wf[4] = {pw.x, pw.y, pw.z, pw.w};
    int vv[4] = {pvs.x, pvs.y, pvs.z, pvs.w};
    #pragma unroll
    for (int j = 0; j < 4; ++j) {
      sa_[qq * ABSTR + kkc + j] = vv[j] ? wf[j] * SCALE : 0.f;
      sb_[qq * ABSTR + kkc + j] = vv[j] ? 0.f : BIGNEG * wf[j];
    }
  };

  f32x4 o0 = {0.f, 0.f, 0.f, 0.f};
  f32x4 o1 = {0.f, 0.f, 0.f, 0.f};
  float m_run[4], l_run[4];
  #pragma unroll
  for (int r = 0; r < 4; ++r) { m_run[r] = BIGNEG; l_run[r] = 0.f; }

  issue(kbase);
  commit();
  __syncthreads();

  for (int kt = 0; kt < TILES_PER_SPLIT; ++kt) {
    if (kt + 1 < TILES_PER_SPLIT) issue(kbase + (kt + 1) * TK);  // loads in flight over compute

    // S = Q K^T (per head)
    f32x4 s[4];
    #pragma unroll
    for (int ks = 0; ks < 4; ++ks) {
      bf16x8 bk = *(const bf16x8*)&lk[(ks * 16 + n16) * KSTR + h * DHEAD + quad * 8];
      f32x4 z = {0.f, 0.f, 0.f, 0.f};
      s[ks] = __builtin_amdgcn_mfma_f32_16x16x32_bf16(aq, bk, z, 0, 0, 0);
    }

    float lvv[4][4];
    #pragma unroll
    for (int ks = 0; ks < 4; ++ks) {
      #pragma unroll
      for (int r = 0; r < 4; ++r) {
        int idx = (quad * 4 + r) * ABSTR + ks * 16 + n16;
        lvv[ks][r] = s[ks][r] * sa_[idx] + sb_[idx];
      }
    }
    float alpha[4];
    #pragma unroll
    for (int r = 0; r < 4; ++r) {
      float tm = fmaxf(fmaxf(lvv[0][r], lvv[1][r]), fmaxf(lvv[2][r], lvv[3][r]));
      tm = fmaxf(tm, __shfl_xor(tm, 1));
      tm = fmaxf(tm, __shfl_xor(tm, 2));
      tm = fmaxf(tm, __shfl_xor(tm, 4));
      tm = fmaxf(tm, __shfl_xor(tm, 8));
      float m_new = fmaxf(m_run[r], tm);
      alpha[r] = __expf(m_run[r] - m_new);
      m_run[r] = m_new;
      float ssum = 0.f;
      #pragma unroll
      for (int ks = 0; ks < 4; ++ks) {
        float p = __expf(fmaxf(lvv[ks][r] - m_new, BIGNEG));
        lvv[ks][r] = p;
        ssum += p;
      }
      ssum += __shfl_xor(ssum, 1);
      ssum += __shfl_xor(ssum, 2);
      ssum += __shfl_xor(ssum, 4);
      ssum += __shfl_xor(ssum, 8);
      l_run[r] = l_run[r] * alpha[r] + ssum;
    }
    #pragma unroll
    for (int ks = 0; ks < 4; ++ks) {
      #pragma unroll
      for (int r = 0; r < 4; ++r)
        lp[h * (TQ * PSTR) + (quad * 4 + r) * PSTR + ks * 16 + n16] = __float2bfloat16(lvv[ks][r]);
    }
    #pragma unroll
    for (int r = 0; r < 4; ++r) { o0[r] *= alpha[r]; o1[r] *= alpha[r]; }

    #pragma unroll
    for (int kk = 0; kk < 2; ++kk) {
      bf16x8 ap  = *(const bf16x8*)&lp[h * (TQ * PSTR) + n16 * PSTR + kk * 32 + quad * 8];
      bf16x8 bv0 = *(const bf16x8*)&lv[(h * DHEAD + n16) * VSTR + kk * 32 + quad * 8];
      bf16x8 bv1 = *(const bf16x8*)&lv[(h * DHEAD + 16 + n16) * VSTR + kk * 32 + quad * 8];
      o0 = __builtin_amdgcn_mfma_f32_16x16x32_bf16(ap, bv0, o0, 0, 0, 0);
      o1 = __builtin_amdgcn_mfma_f32_16x16x32_bf16(ap, bv1, o1, 0, 0, 0);
    }

    if (kt + 1 < TILES_PER_SPLIT) {
      __syncthreads();   // all waves done reading tile kt
      commit();          // regs -> LDS for tile kt+1 (waits vmcnt here, post-compute)
      __syncthreads();   // tile kt+1 visible
    }
  }

  #pragma unroll
  for (int r = 0; r < 4; ++r) {
    int gq = q0 + quad * 4 + r;
    if (gq < NQ) {
      size_t ob = (size_t)split * (NQ * 128) + (size_t)gq * 128 + h * DHEAD;
      Opart[ob + n16] = o0[r];
      Opart[ob + 16 + n16] = o1[r];
      if (n16 == 0) {
        Mpart[((size_t)split * NHEADS + h) * NQ + gq] = m_run[r];
        Lpart[((size_t)split * NHEADS + h) * NQ + gq] = l_run[r];
      }
    }
  }
}

// ============ merge + proj + preLN + MLP + postLN (MFMA), 16 q/block ============
__global__ __launch_bounds__(256) void mlp_kernel(
    const float* __restrict__ Opart, const float* __restrict__ Mpart,
    const float* __restrict__ Lpart,
    const float* __restrict__ skip,
    const __hip_bfloat16* __restrict__ wball,
    const float* __restrict__ bproj,
    const float* __restrict__ pre_g, const float* __restrict__ pre_b,
    const float* __restrict__ b1, const float* __restrict__ b2,
    const float* __restrict__ post_g, const float* __restrict__ post_b,
    float* __restrict__ out)
{
  __shared__ __hip_bfloat16 sab[16][136];
  __shared__ __hip_bfloat16 znb[16][136];
  __shared__ float znf[16][132];
  __shared__ __hip_bfloat16 hb[16][264];
  __shared__ float part[16][4][2];

  const __hip_bfloat16* wprojb = wball + WPROJB;
  const __hip_bfloat16* w1b    = wball + W1B;
  const __hip_bfloat16* w2b    = wball + W2B;

  const int t = threadIdx.x;
  const int q0 = blockIdx.x * TQ;

  // ---- merge k-splits: 16 rows x 128 cols, 8 elems/thread ----
  {
    int row = t >> 4, c0 = (t & 15) * 8;
    int gq = q0 + row; int cq = gq < NQ ? gq : NQ - 1;
    int head = c0 >> 5;
    float m0 = Mpart[(0 * NHEADS + head) * NQ + cq];
    float m1 = Mpart[(1 * NHEADS + head) * NQ + cq];
    float m2 = Mpart[(2 * NHEADS + head) * NQ + cq];
    float mm = fmaxf(m0, fmaxf(m1, m2));
    float e0 = __expf(m0 - mm), e1 = __expf(m1 - mm), e2 = __expf(m2 - mm);
    float ll = Lpart[(0 * NHEADS + head) * NQ + cq] * e0
             + Lpart[(1 * NHEADS + head) * NQ + cq] * e1
             + Lpart[(2 * NHEADS + head) * NQ + cq] * e2;
    float rll = 1.f / fmaxf(ll, 1e-30f);
    const float* p0 = Opart + (size_t)cq * 128 + c0;
    const float* p1 = p0 + (size_t)NQ * 128;
    const float* p2 = p1 + (size_t)NQ * 128;
    #pragma unroll
    for (int i = 0; i < 8; i += 4) {
      float4 a = *(const float4*)(p0 + i);
      float4 b = *(const float4*)(p1 + i);
      float4 c = *(const float4*)(p2 + i);
      sab[row][c0 + i + 0] = __float2bfloat16((a.x * e0 + b.x * e1 + c.x * e2) * rll);
      sab[row][c0 + i + 1] = __float2bfloat16((a.y * e0 + b.y * e1 + c.y * e2) * rll);
      sab[row][c0 + i + 2] = __float2bfloat16((a.z * e0 + b.z * e1 + c.z * e2) * rll);
      sab[row][c0 + i + 3] = __float2bfloat16((a.w * e0 + b.w * e1 + c.w * e2) * rll);
    }
  }
  __syncthreads();

  const int wid = t >> 6, lane = t & 63;
  const int n16 = lane & 15, quad = lane >> 4;
  const int qrow0 = q0 + quad * 4;

  // ---- GEMM1: proj 128->128 ----
  f32x4 acc1[2] = {};
  for (int kt = 0; kt < 4; ++kt) {
    bf16x8 af = *(const bf16x8*)&sab[n16][kt * 32 + quad * 8];
    #pragma unroll
    for (int ni = 0; ni < 2; ++ni) {
      int o = wid * 32 + ni * 16 + n16;
      bf16x8 bw = *(const bf16x8*)(wprojb + (size_t)o * 128 + kt * 32 + quad * 8);
      acc1[ni] = __builtin_amdgcn_mfma_f32_16x16x32_bf16(af, bw, acc1[ni], 0, 0, 0);
    }
  }
  float z[2][4];
  #pragma unroll
  for (int ni = 0; ni < 2; ++ni) {
    int o = wid * 32 + ni * 16 + n16;
    float bo = bproj[o];
    if (qrow0 + 3 < NQ) {
      float4 sk = *(const float4*)(skip + (size_t)o * NQ + qrow0);
      z[ni][0] = acc1[ni][0] + bo + sk.x;
      z[ni][1] = acc1[ni][1] + bo + sk.y;
      z[ni][2] = acc1[ni][2] + bo + sk.z;
      z[ni][3] = acc1[ni][3] + bo + sk.w;
    } else {
      #pragma unroll
      for (int rg = 0; rg < 4; ++rg) {
        int cq = qrow0 + rg < NQ ? qrow0 + rg : NQ - 1;
        z[ni][rg] = acc1[ni][rg] + bo + skip[(size_t)o * NQ + cq];
      }
    }
  }
  // preLN (over 128 outputs spread across 4 waves x 2 ni x 16 n16)
  #pragma unroll
  for (int rg = 0; rg < 4; ++rg) {
    float s = z[0][rg] + z[1][rg];
    float ss = z[0][rg] * z[0][rg] + z[1][rg] * z[1][rg];
    s += __shfl_xor(s, 1);  ss += __shfl_xor(ss, 1);
    s += __shfl_xor(s, 2);  ss += __shfl_xor(ss, 2);
    s += __shfl_xor(s, 4);  ss += __shfl_xor(ss, 4);
    s += __shfl_xor(s, 8);  ss += __shfl_xor(ss, 8);
    if (n16 == 0) { part[quad * 4 + rg][wid][0] = s; part[quad * 4 + rg][wid][1] = ss; }
  }
  __syncthreads();
  #pragma unroll
  for (int rg = 0; rg < 4; ++rg) {
    int row = quad * 4 + rg;
    float S  = part[row][0][0] + part[row][1][0] + part[row][2][0] + part[row][3][0];
    float SS = part[row][0][1] + part[row][1][1] + part[row][2][1] + part[row][3][1];
    float mean = S * (1.f / 128.f);
    float var  = SS * (1.f / 128.f) - mean * mean;
    float rstd = rsqrtf(fmaxf(var, 0.f) + 1e-5f);
    #pragma unroll
    for (int ni = 0; ni < 2; ++ni) {
      int o = wid * 32 + ni * 16 + n16;
      float zn = (z[ni][rg] - mean) * rstd * pre_g[o] + pre_b[o];
      znf[row][o] = zn;
      znb[row][o] = __float2bfloat16(zn);
    }
  }
  __syncthreads();

  // ---- GEMM2: 128 -> 256 + GELU ----
  f32x4 acc2[4] = {};
  for (int kt = 0; kt < 4; ++kt) {
    bf16x8 af = *(const bf16x8*)&znb[n16][kt * 32 + quad * 8];
    #pragma unroll
    for (int ni = 0; ni < 4; ++ni) {
      int j = wid * 64 + ni * 16 + n16;
      bf16x8 bw = *(const bf16x8*)(w1b + (size_t)j * 128 + kt * 32 + quad * 8);
      acc2[ni] = __builtin_amdgcn_mfma_f32_16x16x32_bf16(af, bw, acc2[ni], 0, 0, 0);
    }
  }
  #pragma unroll
  for (int ni = 0; ni < 4; ++ni) {
    int j = wid * 64 + ni * 16 + n16;
    float bj = b1[j];
    #pragma unroll
    for (int rg = 0; rg < 4; ++rg) {
      float a1 = acc2[ni][rg] + bj;
      hb[quad * 4 + rg][j] = __float2bfloat16(0.5f * a1 * (1.0f + erff(a1 * 0.70710678118654752f)));
    }
  }
  __syncthreads();

  // ---- GEMM3: 256 -> 128 + residual + postLN ----
  f32x4 acc3[2] = {};
  for (int kt = 0; kt < 8; ++kt) {
    bf16x8 af = *(const bf16x8*)&hb[n16][kt * 32 + quad * 8];
    #pragma unroll
    for (int ni = 0; ni < 2; ++ni) {
      int o = wid * 32 + ni * 16 + n16;
      bf16x8 bw = *(const bf16x8*)(w2b + (size_t)o * 256 + kt * 32 + quad * 8);
      acc3[ni] = __builtin_amdgcn_mfma_f32_16x16x32_bf16(af, bw, acc3[ni], 0, 0, 0);
    }
  }
  float y[2][4];
  #pragma unroll
  for (int ni = 0; ni < 2; ++ni) {
    int o = wid * 32 + ni * 16 + n16;
    float bo = b2[o];
    #pragma unroll
    for (int rg = 0; rg < 4; ++rg)
      y[ni][rg] = znf[quad * 4 + rg][o] + acc3[ni][rg] + bo;
  }
  #pragma unroll
  for (int rg = 0; rg < 4; ++rg) {
    float s = y[0][rg] + y[1][rg];
    float ss = y[0][rg] * y[0][rg] + y[1][rg] * y[1][rg];
    s += __shfl_xor(s, 1);  ss += __shfl_xor(ss, 1);
    s += __shfl_xor(s, 2);  ss += __shfl_xor(ss, 2);
    s += __shfl_xor(s, 4);  ss += __shfl_xor(ss, 4);
    s += __shfl_xor(s, 8);  ss += __shfl_xor(ss, 8);
    if (n16 == 0) { part[quad * 4 + rg][wid][0] = s; part[quad * 4 + rg][wid][1] = ss; }
  }
  __syncthreads();
  #pragma unroll
  for (int rg = 0; rg < 4; ++rg) {
    int row = quad * 4 + rg;
    float S  = part[row][0][0] + part[row][1][0] + part[row][2][0] + part[row][3][0];
    float SS = part[row][0][1] + part[row][1][1] + part[row][2][1] + part[row][3][1];
    float mean = S * (1.f / 128.f);
    float var  = SS * (1.f / 128.f) - mean * mean;
    float rstd = rsqrtf(fmaxf(var, 0.f) + 1e-5f);
    #pragma unroll
    for (int ni = 0; ni < 2; ++ni) {
      int o = wid * 32 + ni * 16 + n16;
      y[ni][rg] = (y[ni][rg] - mean) * rstd * post_g[o] + post_b[o];
    }
  }
  #pragma unroll
  for (int ni = 0; ni < 2; ++ni) {
    int o = wid * 32 + ni * 16 + n16;
    if (qrow0 + 3 < NQ) {
      *(float4*)(out + (size_t)o * NQ + qrow0) = make_float4(y[ni][0], y[ni][1], y[ni][2], y[ni][3]);
    } else {
      #pragma unroll
      for (int rg = 0; rg < 4; ++rg)
        if (qrow0 + rg < NQ) out[(size_t)o * NQ + qrow0 + rg] = y[ni][rg];
    }
  }
}

extern "C" void kernel_launch(void* const* d_in, const int* in_sizes, int n_in,
                              void* d_out, int out_size, void* d_ws, size_t ws_size,
                              hipStream_t stream) {
  if (ws_size < (size_t)WS_REQ) return;

  const float* q     = (const float*)d_in[0];
  const float* k     = (const float*)d_in[1];
  const float* v     = (const float*)d_in[2];
  const float* Wl    = (const float*)d_in[3];
  const int*   vis   = (const int*)d_in[4];
  const float* skip  = (const float*)d_in[5];
  const float* qn_g  = (const float*)d_in[6];
  const float* qn_b  = (const float*)d_in[7];
  const float* kn_g  = (const float*)d_in[8];
  const float* kn_b  = (const float*)d_in[9];
  const float* vn_g  = (const float*)d_in[10];
  const float* vn_b  = (const float*)d_in[11];
  const float* wq    = (const float*)d_in[12];
  const float* bq    = (const float*)d_in[13];
  const float* wk    = (const float*)d_in[14];
  const float* bk    = (const float*)d_in[15];
  const float* wv    = (const float*)d_in[16];
  const float* bv    = (const float*)d_in[17];
  const float* wproj = (const float*)d_in[18];
  const float* bproj = (const float*)d_in[19];
  const float* pre_g = (const float*)d_in[20];
  const float* pre_b = (const float*)d_in[21];
  const float* w1    = (const float*)d_in[22];
  const float* b1    = (const float*)d_in[23];
  const float* w2    = (const float*)d_in[24];
  const float* b2    = (const float*)d_in[25];
  const float* post_g= (const float*)d_in[26];
  const float* post_b= (const float*)d_in[27];

  char* ws = (char*)d_ws;
  __hip_bfloat16* Qp = (__hip_bfloat16*)(ws + WS_QP);
  __hip_bfloat16* Kp = (__hip_bfloat16*)(ws + WS_KP);
  __hip_bfloat16* Vt = (__hip_bfloat16*)(ws + WS_VT);
  float* Opart = (float*)(ws + WS_OP);
  float* Mpart = (float*)(ws + WS_MP);
  float* Lpart = (float*)(ws + WS_LP);
  __hip_bfloat16* Wb = (__hip_bfloat16*)(ws + WS_WB);

  hipLaunchKernelGGL(wconv_kernel, dim3(128), dim3(256), 0, stream,
                     wq, wk, wv, wproj, w1, w2, Wb);

  hipLaunchKernelGGL(lnproj_kernel, dim3(475), dim3(128), 0, stream,
                     q, k, v, qn_g, qn_b, kn_g, kn_b, vn_g, vn_b,
                     Wb, bq, bk, bv, Qp, Kp, Vt);

  hipLaunchKernelGGL(attn_kernel, dim3(QBLOCKS, KSPLIT), dim3(256), 0, stream,
                     Qp, Kp, Vt, Wl, vis, Opart, Mpart, Lpart);

  hipLaunchKernelGGL(mlp_kernel, dim3(QBLOCKS), dim3(256), 0, stream,
                     Opart, Mpart, Lpart, skip, Wb, bproj, pre_g, pre_b,
                     b1, b2, post_g, post_b, (float*)d_out);
}